// Round 17
// baseline (177.797 us; speedup 1.0000x reference)
//
#include <hip/hip_runtime.h>

#define DM 512
#define NH 8
#define DK 64
#define SEQ 4096

typedef short bf16x8 __attribute__((ext_vector_type(8)));
typedef float f32x4 __attribute__((ext_vector_type(4)));
typedef unsigned short u16;
typedef u16 u16x8 __attribute__((ext_vector_type(8)));
typedef u16 u16x4 __attribute__((ext_vector_type(4)));
typedef unsigned int u32;
typedef u32 u32x2 __attribute__((ext_vector_type(2)));

__device__ __forceinline__ u16 f2bf(float f) {
  union { float f; unsigned u; } v; v.f = f;
  unsigned r = v.u + 0x7fffu + ((v.u >> 16) & 1u);
  return (u16)(r >> 16);
}

__device__ __forceinline__ u32 cvtpk(float a, float b) {
  u32 r; asm("v_cvt_pk_bf16_f32 %0, %1, %2" : "=v"(r) : "v"(a), "v"(b)); return r;
}

__device__ __forceinline__ float fexp2(float x) {
  float r; asm("v_exp_f32 %0, %1" : "=v"(r) : "v"(x)); return r;
}

__device__ __forceinline__ float fmax3(float a, float b, float c) {
  return fmaxf(fmaxf(a, b), c);  // fuses to v_max3_f32
}

// ---- merged Q/K/V projection GEMM: 128x128 tiles, cvtpk staging.
// Grid 768 = 3 modes x 256, XCD-locality swizzle.
// __launch_bounds__(256,3): LDS 36.9KB*3=110.6KB fits -> all 768 blocks
// co-resident (one dispatch round instead of 1.5; no half-empty tail).
// mode 0: Qh * (0.125*log2 e); 1: Kh; 2: Vt (transposed).
__global__ __launch_bounds__(256, 3)
void gemm_qkv(const float* __restrict__ qx, const float* __restrict__ kx,
              const float* __restrict__ vx,
              const float* __restrict__ wq, const float* __restrict__ bq,
              const float* __restrict__ wk, const float* __restrict__ bk,
              const float* __restrict__ wv, const float* __restrict__ bv,
              u16* __restrict__ Qh, u16* __restrict__ Kh, u16* __restrict__ Vt)
{
  __shared__ alignas(16) u16 Alds[128][72];
  __shared__ alignas(16) u16 Blds[128][72];
  const int mode = blockIdx.x >> 8;
  const int d = blockIdx.x & 255;
  const int xcd = d & 7, inner = d >> 3;
  const int bx = (xcd << 3) + (inner >> 2);  // 0..63 m-tile
  const int by = inner & 3;                  // 0..3  n-tile
  const float* X = (mode == 0) ? qx : (mode == 1) ? kx : vx;
  const float* W = (mode == 0) ? wq : (mode == 1) ? wk : wv;
  const float* Bs = (mode == 0) ? bq : (mode == 1) ? bk : bv;

  const int t = threadIdx.x;
  const int m0 = bx << 7, n0 = by << 7;
  const int lane = t & 63, w = t >> 6;
  const int lr = lane & 15, lg = lane >> 4;
  const int wr = w >> 1, wc = w & 1;

  f32x4 acc[4][4];
  #pragma unroll
  for (int i = 0; i < 4; ++i)
    #pragma unroll
    for (int j = 0; j < 4; ++j) acc[i][j] = (f32x4){0.f, 0.f, 0.f, 0.f};

  float4 xa[8], wb[8];
  auto loadX = [&](int k0) {
    #pragma unroll
    for (int i = 0; i < 8; ++i) {
      int f = (i << 8) + t;
      xa[i] = *(const float4*)(X + (size_t)(m0 + (f >> 4)) * 512 + k0 + ((f & 15) << 2));
      wb[i] = *(const float4*)(W + (size_t)(n0 + (f >> 4)) * 512 + k0 + ((f & 15) << 2));
    }
  };

  loadX(0);
  for (int k0 = 0; k0 < 512; k0 += 64) {
    __syncthreads();
    #pragma unroll
    for (int i = 0; i < 8; ++i) {
      int f = (i << 8) + t;
      u32x2 pa = { cvtpk(xa[i].x, xa[i].y), cvtpk(xa[i].z, xa[i].w) };
      *(u32x2*)&Alds[f >> 4][(f & 15) << 2] = pa;
      u32x2 pb = { cvtpk(wb[i].x, wb[i].y), cvtpk(wb[i].z, wb[i].w) };
      *(u32x2*)&Blds[f >> 4][(f & 15) << 2] = pb;
    }
    __syncthreads();
    if (k0 + 64 < 512) loadX(k0 + 64);  // T14: prefetch hides under MFMA

    #pragma unroll
    for (int kk = 0; kk < 2; ++kk) {
      bf16x8 af[4], bfr[4];
      #pragma unroll
      for (int mi = 0; mi < 4; ++mi)
        af[mi] = *(const bf16x8*)&Alds[(wr << 6) + (mi << 4) + lr][(kk << 5) + (lg << 3)];
      #pragma unroll
      for (int ni = 0; ni < 4; ++ni)
        bfr[ni] = *(const bf16x8*)&Blds[(wc << 6) + (ni << 4) + lr][(kk << 5) + (lg << 3)];
      #pragma unroll
      for (int mi = 0; mi < 4; ++mi)
        #pragma unroll
        for (int ni = 0; ni < 4; ++ni)
          acc[mi][ni] = __builtin_amdgcn_mfma_f32_16x16x32_bf16(af[mi], bfr[ni], acc[mi][ni], 0, 0, 0);
    }
  }

  const float sc = (mode == 0) ? 0.18033688f : 1.0f;  // 0.125*log2(e) for Q
  #pragma unroll
  for (int mi = 0; mi < 4; ++mi) {
    #pragma unroll
    for (int ni = 0; ni < 4; ++ni) {
      const int e = n0 + (wc << 6) + (ni << 4) + lr;
      const int m = m0 + (wr << 6) + (mi << 4) + (lg << 2);
      const float bb = Bs[e];
      const int b = m >> 12, s = m & 4095, h = e >> 6, dk = e & 63;
      if (mode != 2) {
        u16* O = (mode == 0) ? Qh : Kh;
        size_t base = ((size_t)((b << 3) + h) * SEQ + s) * DK + dk;
        #pragma unroll
        for (int r = 0; r < 4; ++r)
          O[base + (size_t)r * DK] = f2bf((acc[mi][ni][r] + bb) * sc);
      } else {
        size_t base = ((size_t)((b << 3) + h) * DK + dk) * SEQ + s;
        u16x4 p = { f2bf(acc[mi][ni][0] + bb), f2bf(acc[mi][ni][1] + bb),
                    f2bf(acc[mi][ni][2] + bb), f2bf(acc[mi][ni][3] + bb) };
        *(u16x4*)(Vt + base) = p;
      }
    }
  }
}

// ---- output projection, 128x128 tiles, cvtpk W-staging, bf16 -> fp32 ----
__global__ __launch_bounds__(256, 2)
void gemm_out(const u16* __restrict__ Xa, const float* __restrict__ W,
              const float* __restrict__ bias, float* __restrict__ Out)
{
  __shared__ alignas(16) u16 Alds[128][72];
  __shared__ alignas(16) u16 Blds[128][72];
  const int d = blockIdx.x;
  const int xcd = d & 7, inner = d >> 3;
  const int bx = (xcd << 3) + (inner >> 2);
  const int by = inner & 3;

  const int t = threadIdx.x;
  const int m0 = bx << 7, n0 = by << 7;
  const int lane = t & 63, w = t >> 6;
  const int lr = lane & 15, lg = lane >> 4;
  const int wr = w >> 1, wc = w & 1;

  f32x4 acc[4][4];
  #pragma unroll
  for (int i = 0; i < 4; ++i)
    #pragma unroll
    for (int j = 0; j < 4; ++j) acc[i][j] = (f32x4){0.f, 0.f, 0.f, 0.f};

  u16x8 xa3[4]; float4 wb[8];
  auto loadX = [&](int k0) {
    #pragma unroll
    for (int i = 0; i < 4; ++i) {
      int f = (i << 8) + t;
      xa3[i] = *(const u16x8*)(Xa + (size_t)(m0 + (f >> 3)) * 512 + k0 + ((f & 7) << 3));
    }
    #pragma unroll
    for (int i = 0; i < 8; ++i) {
      int f = (i << 8) + t;
      wb[i] = *(const float4*)(W + (size_t)(n0 + (f >> 4)) * 512 + k0 + ((f & 15) << 2));
    }
  };

  loadX(0);
  for (int k0 = 0; k0 < 512; k0 += 64) {
    __syncthreads();
    #pragma unroll
    for (int i = 0; i < 4; ++i) {
      int f = (i << 8) + t;
      *(u16x8*)&Alds[f >> 3][(f & 7) << 3] = xa3[i];
    }
    #pragma unroll
    for (int i = 0; i < 8; ++i) {
      int f = (i << 8) + t;
      u32x2 p = { cvtpk(wb[i].x, wb[i].y), cvtpk(wb[i].z, wb[i].w) };
      *(u32x2*)&Blds[f >> 4][(f & 15) << 2] = p;
    }
    __syncthreads();
    if (k0 + 64 < 512) loadX(k0 + 64);

    #pragma unroll
    for (int kk = 0; kk < 2; ++kk) {
      bf16x8 af[4], bfr[4];
      #pragma unroll
      for (int mi = 0; mi < 4; ++mi)
        af[mi] = *(const bf16x8*)&Alds[(wr << 6) + (mi << 4) + lr][(kk << 5) + (lg << 3)];
      #pragma unroll
      for (int ni = 0; ni < 4; ++ni)
        bfr[ni] = *(const bf16x8*)&Blds[(wc << 6) + (ni << 4) + lr][(kk << 5) + (lg << 3)];
      #pragma unroll
      for (int mi = 0; mi < 4; ++mi)
        #pragma unroll
        for (int ni = 0; ni < 4; ++ni)
          acc[mi][ni] = __builtin_amdgcn_mfma_f32_16x16x32_bf16(af[mi], bfr[ni], acc[mi][ni], 0, 0, 0);
    }
  }

  #pragma unroll
  for (int mi = 0; mi < 4; ++mi) {
    #pragma unroll
    for (int ni = 0; ni < 4; ++ni) {
      const int e = n0 + (wc << 6) + (ni << 4) + lr;
      const int m = m0 + (wr << 6) + (mi << 4) + (lg << 2);
      const float bb = bias[e];
      size_t base = (size_t)m * 512 + e;
      #pragma unroll
      for (int r = 0; r < 4; ++r) Out[base + (size_t)r * 512] = acc[mi][ni][r] + bb;
    }
  }
}

// ---- Flash attention: r16 validated (C-init = -mrun, sequential mi, dual P,
//      dbuf 1-barrier staging). Unchanged. Grid 512 = 16 bh x 32 q-tiles. ----
__global__ __launch_bounds__(256, 2)
void attn_kernel(const u16* __restrict__ Qh, const u16* __restrict__ Kh,
                 const u16* __restrict__ Vt, u16* __restrict__ Xa)
{
  // u16 units: buf0 K [0..4095], buf0 V [4096..8191],
  //            buf1 K [8192..12287], buf1 V [12288..16383],
  //            P: 2 regions x 4 waves x [16][72]  [16384..25599]
  __shared__ alignas(1024) u16 smem[25600];

  const int t = threadIdx.x;
  const int lane = t & 63, w = t >> 6;
  const int lr = lane & 15, lg = lane >> 4;
  const int ob = ((blockIdx.x & 7) << 6) + (blockIdx.x >> 3);  // XCD-bijective (512%8==0)
  const int qb = ob & 31, bh = ob >> 5;
  const size_t qkbase = (size_t)bh * SEQ * DK;
  const size_t vbase  = (size_t)bh * DK * SEQ;
  u16* Pm[2] = { smem + 16384 + w * 1152, smem + 16384 + 4608 + w * 1152 };

  bf16x8 qf[2][2];
  #pragma unroll
  for (int mi = 0; mi < 2; ++mi)
    #pragma unroll
    for (int kk = 0; kk < 2; ++kk) {
      int qrow = (qb << 7) + (w << 5) + (mi << 4) + lr;
      qf[mi][kk] = *(const bf16x8*)(Qh + qkbase + (size_t)qrow * DK + (kk << 5) + (lg << 3));
    }

  bf16x8 onesf;
  {
    u16 one = (lr == 0) ? (u16)0x3F80 : (u16)0;
    #pragma unroll
    for (int j = 0; j < 8; ++j) onesf[j] = (short)one;
  }

  // mrun starts at 0: scores bounded (|s| << 127 in exp2 domain), so the
  // first tiles run un-shifted; defer-max keeps P <= 2^8 thereafter.
  float mrun[2] = {0.f, 0.f};
  f32x4 o[2][4], osum[2];
  #pragma unroll
  for (int mi = 0; mi < 2; ++mi) {
    #pragma unroll
    for (int dt = 0; dt < 4; ++dt) o[mi][dt] = (f32x4){0.f, 0.f, 0.f, 0.f};
    osum[mi] = (f32x4){0.f, 0.f, 0.f, 0.f};
  }

  const u16* Kg = Kh + qkbase;
  const u16* Vg = Vt + vbase;
  const int r0 = t >> 3, c0 = t & 7;
  const int r1 = r0 + 32;
  const int wk0 = r0 * 64 + ((c0 ^ (r0 & 7)) << 3);  // swizzled LDS offsets (u16)
  const int wk1 = r1 * 64 + ((c0 ^ (r1 & 7)) << 3);

  u16x8 kr0, kr1, vr0, vr1;
  auto GLOAD = [&](int it2) {
    const int kv0 = it2 << 6;
    kr0 = *(const u16x8*)(Kg + (size_t)(kv0 + r0) * 64 + (c0 << 3));
    kr1 = *(const u16x8*)(Kg + (size_t)(kv0 + r1) * 64 + (c0 << 3));
    vr0 = *(const u16x8*)(Vg + (size_t)r0 * SEQ + kv0 + (c0 << 3));
    vr1 = *(const u16x8*)(Vg + (size_t)r1 * SEQ + kv0 + (c0 << 3));
  };
  auto WRITE = [&](int buf) {
    u16* B = smem + buf * 8192;
    *(u16x8*)&B[wk0]        = kr0;
    *(u16x8*)&B[wk1]        = kr1;
    *(u16x8*)&B[4096 + wk0] = vr0;
    *(u16x8*)&B[4096 + wk1] = vr1;
  };

  GLOAD(0); WRITE(0); GLOAD(1);

  for (int it = 0; it < SEQ / 64; ++it) {
    const int cur = it & 1;
    __syncthreads();

    const u16* Kb = smem + cur * 8192;
    const u16* Vb = Kb + 4096;
    bf16x8 kf[4][2], vf[4][2];
    #pragma unroll
    for (int nt = 0; nt < 4; ++nt)
      #pragma unroll
      for (int kk = 0; kk < 2; ++kk) {
        const int off = ((nt << 4) + lr) * 64 + ((((kk << 2) + lg) ^ (lr & 7)) << 3);
        kf[nt][kk] = *(const bf16x8*)&Kb[off];
        vf[nt][kk] = *(const bf16x8*)&Vb[off];
      }

    if (it + 1 < SEQ / 64) WRITE(cur ^ 1);
    if (it + 2 < SEQ / 64) GLOAD(it + 2);

    #pragma unroll
    for (int mi = 0; mi < 2; ++mi) {
      u16* Pw = Pm[mi];
      const float mm = mrun[mi];
      // S' = K*Q^T - mm : shift baked into the accumulator init
      f32x4 s[4];
      const f32x4 ci = (f32x4){-mm, -mm, -mm, -mm};
      #pragma unroll
      for (int nt = 0; nt < 4; ++nt) s[nt] = ci;
      #pragma unroll
      for (int kk = 0; kk < 2; ++kk)
        #pragma unroll
        for (int nt = 0; nt < 4; ++nt)
          s[nt] = __builtin_amdgcn_mfma_f32_16x16x32_bf16(kf[nt][kk], qf[mi][kk], s[nt], 0, 0, 0);

      // lane-local partial max of shifted scores; ballot reduces across lanes
      float m0 = fmax3(s[0][0], s[0][1], s[0][2]);
      float m1 = fmax3(s[0][3], s[1][0], s[1][1]);
      float m2 = fmax3(s[1][2], s[1][3], s[2][0]);
      float m3 = fmax3(s[2][1], s[2][2], s[2][3]);
      float m4 = fmax3(s[3][0], s[3][1], s[3][2]);
      float pmax = fmaxf(fmax3(m0, m1, m2), fmax3(m3, m4, s[3][3]));

      if (!__all(pmax <= 8.f)) {  // rare fix-up: shift grew past THR=8
        float tmax = fmaxf(pmax, __shfl_xor(pmax, 16));
        tmax = fmaxf(tmax, __shfl_xor(tmax, 32));  // > 8 > 0 when taken
        float scl = fexp2(-tmax);
        mrun[mi] = mm + tmax;
        osum[mi][0] *= scl;
        #pragma unroll
        for (int dt = 0; dt < 4; ++dt) o[mi][dt] *= scl;
        #pragma unroll
        for (int nt = 0; nt < 4; ++nt) s[nt] = s[nt] - tmax;
      }

      // exps: no subtraction on the common path
      #pragma unroll
      for (int nt = 0; nt < 4; ++nt) {
        float e0 = fexp2(s[nt][0]), e1 = fexp2(s[nt][1]);
        float e2 = fexp2(s[nt][2]), e3 = fexp2(s[nt][3]);
        u32x2 pk2 = { cvtpk(e0, e1), cvtpk(e2, e3) };
        *(u32x2*)((char*)Pw + lr * 144 + (nt << 5) + (lg << 3)) = pk2;
      }

      // O^T += V * P^T ; l(row 0 of D) += ones * P^T
      #pragma unroll
      for (int kk = 0; kk < 2; ++kk) {
        bf16x8 pf = *(const bf16x8*)&Pw[lr * 72 + (kk << 5) + (lg << 3)];
        #pragma unroll
        for (int dt = 0; dt < 4; ++dt)
          o[mi][dt] = __builtin_amdgcn_mfma_f32_16x16x32_bf16(vf[dt][kk], pf, o[mi][dt], 0, 0, 0);
        osum[mi] = __builtin_amdgcn_mfma_f32_16x16x32_bf16(onesf, pf, osum[mi], 0, 0, 0);
      }
    }
  }
  __syncthreads();

  #pragma unroll
  for (int mi = 0; mi < 2; ++mi) {
    float lsum = __shfl(osum[mi][0], lr);
    float inv = 1.f / lsum;
    #pragma unroll
    for (int dt = 0; dt < 4; ++dt) {
      u16x4 v4 = { f2bf(o[mi][dt][0] * inv), f2bf(o[mi][dt][1] * inv),
                   f2bf(o[mi][dt][2] * inv), f2bf(o[mi][dt][3] * inv) };
      int row = (w << 5) + (mi << 4) + lr;
      *(u16x4*)&smem[row * 72 + (dt << 4) + (lg << 2)] = v4;
    }
  }
  __syncthreads();
  {
    const int b = bh >> 3, h = bh & 7;
    #pragma unroll
    for (int i = 0; i < 4; ++i) {
      int f = (i << 8) + t;
      int row = f >> 3, c8 = (f & 7) << 3;
      u16x8 val = *(const u16x8*)&smem[row * 72 + c8];
      *(u16x8*)(Xa + ((size_t)b * SEQ + (qb << 7) + row) * DM + (h << 6) + c8) = val;
    }
  }
}

extern "C" void kernel_launch(void* const* d_in, const int* in_sizes, int n_in,
                              void* d_out, int out_size, void* d_ws, size_t ws_size,
                              hipStream_t stream)
{
  const float* q  = (const float*)d_in[0];
  const float* k  = (const float*)d_in[1];
  const float* v  = (const float*)d_in[2];
  const float* wq = (const float*)d_in[3];
  const float* bq = (const float*)d_in[4];
  const float* wk = (const float*)d_in[5];
  const float* bk = (const float*)d_in[6];
  const float* wv = (const float*)d_in[7];
  const float* bv = (const float*)d_in[8];
  const float* wo = (const float*)d_in[9];
  const float* bo = (const float*)d_in[10];

  const size_t HS = (size_t)2 * NH * SEQ * DK;
  u16* Qh = (u16*)d_ws;
  u16* Kh = Qh + HS;
  u16* Vt = Kh + HS;
  u16* Xa = Vt + HS;

  gemm_qkv<<<768, 256, 0, stream>>>(q, k, v, wq, bq, wk, bk, wv, bv, Qh, Kh, Vt);
  attn_kernel<<<512, 256, 0, stream>>>(Qh, Kh, Vt, Xa);
  gemm_out<<<256, 256, 0, stream>>>(Xa, wo, bo, (float*)d_out);
}

// Round 18
// 129.340 us; speedup vs baseline: 1.3747x; 1.3747x over previous
//
#include <hip/hip_runtime.h>

#define DM 512
#define NH 8
#define DK 64
#define SEQ 4096

typedef short bf16x8 __attribute__((ext_vector_type(8)));
typedef float f32x4 __attribute__((ext_vector_type(4)));
typedef unsigned short u16;
typedef u16 u16x8 __attribute__((ext_vector_type(8)));
typedef u16 u16x4 __attribute__((ext_vector_type(4)));
typedef unsigned int u32;
typedef u32 u32x2 __attribute__((ext_vector_type(2)));

__device__ __forceinline__ u16 f2bf(float f) {
  union { float f; unsigned u; } v; v.f = f;
  unsigned r = v.u + 0x7fffu + ((v.u >> 16) & 1u);
  return (u16)(r >> 16);
}

__device__ __forceinline__ u32 cvtpk(float a, float b) {
  u32 r; asm("v_cvt_pk_bf16_f32 %0, %1, %2" : "=v"(r) : "v"(a), "v"(b)); return r;
}

__device__ __forceinline__ float fexp2(float x) {
  float r; asm("v_exp_f32 %0, %1" : "=v"(r) : "v"(x)); return r;
}

__device__ __forceinline__ float fmax3(float a, float b, float c) {
  return fmaxf(fmaxf(a, b), c);  // fuses to v_max3_f32
}

// ---- merged Q/K/V projection GEMM: 128x128 tiles, cvtpk staging.
// Grid 768 = 3 modes x 256, XCD-locality swizzle. __launch_bounds__(256,2):
// r17 showed (256,3) forces VGPR 84 -> spills xa/wb/acc -> 5x slowdown.
// mode 0: Qh * (0.125*log2 e); 1: Kh; 2: Vt (transposed).
__global__ __launch_bounds__(256, 2)
void gemm_qkv(const float* __restrict__ qx, const float* __restrict__ kx,
              const float* __restrict__ vx,
              const float* __restrict__ wq, const float* __restrict__ bq,
              const float* __restrict__ wk, const float* __restrict__ bk,
              const float* __restrict__ wv, const float* __restrict__ bv,
              u16* __restrict__ Qh, u16* __restrict__ Kh, u16* __restrict__ Vt)
{
  __shared__ alignas(16) u16 Alds[128][72];
  __shared__ alignas(16) u16 Blds[128][72];
  const int mode = blockIdx.x >> 8;
  const int d = blockIdx.x & 255;
  const int xcd = d & 7, inner = d >> 3;
  const int bx = (xcd << 3) + (inner >> 2);  // 0..63 m-tile
  const int by = inner & 3;                  // 0..3  n-tile
  const float* X = (mode == 0) ? qx : (mode == 1) ? kx : vx;
  const float* W = (mode == 0) ? wq : (mode == 1) ? wk : wv;
  const float* Bs = (mode == 0) ? bq : (mode == 1) ? bk : bv;

  const int t = threadIdx.x;
  const int m0 = bx << 7, n0 = by << 7;
  const int lane = t & 63, w = t >> 6;
  const int lr = lane & 15, lg = lane >> 4;
  const int wr = w >> 1, wc = w & 1;

  f32x4 acc[4][4];
  #pragma unroll
  for (int i = 0; i < 4; ++i)
    #pragma unroll
    for (int j = 0; j < 4; ++j) acc[i][j] = (f32x4){0.f, 0.f, 0.f, 0.f};

  float4 xa[8], wb[8];
  auto loadX = [&](int k0) {
    #pragma unroll
    for (int i = 0; i < 8; ++i) {
      int f = (i << 8) + t;
      xa[i] = *(const float4*)(X + (size_t)(m0 + (f >> 4)) * 512 + k0 + ((f & 15) << 2));
      wb[i] = *(const float4*)(W + (size_t)(n0 + (f >> 4)) * 512 + k0 + ((f & 15) << 2));
    }
  };

  loadX(0);
  for (int k0 = 0; k0 < 512; k0 += 64) {
    __syncthreads();
    #pragma unroll
    for (int i = 0; i < 8; ++i) {
      int f = (i << 8) + t;
      u32x2 pa = { cvtpk(xa[i].x, xa[i].y), cvtpk(xa[i].z, xa[i].w) };
      *(u32x2*)&Alds[f >> 4][(f & 15) << 2] = pa;
      u32x2 pb = { cvtpk(wb[i].x, wb[i].y), cvtpk(wb[i].z, wb[i].w) };
      *(u32x2*)&Blds[f >> 4][(f & 15) << 2] = pb;
    }
    __syncthreads();
    if (k0 + 64 < 512) loadX(k0 + 64);  // T14: prefetch hides under MFMA

    #pragma unroll
    for (int kk = 0; kk < 2; ++kk) {
      bf16x8 af[4], bfr[4];
      #pragma unroll
      for (int mi = 0; mi < 4; ++mi)
        af[mi] = *(const bf16x8*)&Alds[(wr << 6) + (mi << 4) + lr][(kk << 5) + (lg << 3)];
      #pragma unroll
      for (int ni = 0; ni < 4; ++ni)
        bfr[ni] = *(const bf16x8*)&Blds[(wc << 6) + (ni << 4) + lr][(kk << 5) + (lg << 3)];
      #pragma unroll
      for (int mi = 0; mi < 4; ++mi)
        #pragma unroll
        for (int ni = 0; ni < 4; ++ni)
          acc[mi][ni] = __builtin_amdgcn_mfma_f32_16x16x32_bf16(af[mi], bfr[ni], acc[mi][ni], 0, 0, 0);
    }
  }

  const float sc = (mode == 0) ? 0.18033688f : 1.0f;  // 0.125*log2(e) for Q
  #pragma unroll
  for (int mi = 0; mi < 4; ++mi) {
    #pragma unroll
    for (int ni = 0; ni < 4; ++ni) {
      const int e = n0 + (wc << 6) + (ni << 4) + lr;
      const int m = m0 + (wr << 6) + (mi << 4) + (lg << 2);
      const float bb = Bs[e];
      const int b = m >> 12, s = m & 4095, h = e >> 6, dk = e & 63;
      if (mode != 2) {
        u16* O = (mode == 0) ? Qh : Kh;
        size_t base = ((size_t)((b << 3) + h) * SEQ + s) * DK + dk;
        #pragma unroll
        for (int r = 0; r < 4; ++r)
          O[base + (size_t)r * DK] = f2bf((acc[mi][ni][r] + bb) * sc);
      } else {
        size_t base = ((size_t)((b << 3) + h) * DK + dk) * SEQ + s;
        u16x4 p = { f2bf(acc[mi][ni][0] + bb), f2bf(acc[mi][ni][1] + bb),
                    f2bf(acc[mi][ni][2] + bb), f2bf(acc[mi][ni][3] + bb) };
        *(u16x4*)(Vt + base) = p;
      }
    }
  }
}

// ---- output projection, 128x128 tiles, cvtpk W-staging, bf16 -> fp32 ----
__global__ __launch_bounds__(256, 2)
void gemm_out(const u16* __restrict__ Xa, const float* __restrict__ W,
              const float* __restrict__ bias, float* __restrict__ Out)
{
  __shared__ alignas(16) u16 Alds[128][72];
  __shared__ alignas(16) u16 Blds[128][72];
  const int d = blockIdx.x;
  const int xcd = d & 7, inner = d >> 3;
  const int bx = (xcd << 3) + (inner >> 2);
  const int by = inner & 3;

  const int t = threadIdx.x;
  const int m0 = bx << 7, n0 = by << 7;
  const int lane = t & 63, w = t >> 6;
  const int lr = lane & 15, lg = lane >> 4;
  const int wr = w >> 1, wc = w & 1;

  f32x4 acc[4][4];
  #pragma unroll
  for (int i = 0; i < 4; ++i)
    #pragma unroll
    for (int j = 0; j < 4; ++j) acc[i][j] = (f32x4){0.f, 0.f, 0.f, 0.f};

  u16x8 xa3[4]; float4 wb[8];
  auto loadX = [&](int k0) {
    #pragma unroll
    for (int i = 0; i < 4; ++i) {
      int f = (i << 8) + t;
      xa3[i] = *(const u16x8*)(Xa + (size_t)(m0 + (f >> 3)) * 512 + k0 + ((f & 7) << 3));
    }
    #pragma unroll
    for (int i = 0; i < 8; ++i) {
      int f = (i << 8) + t;
      wb[i] = *(const float4*)(W + (size_t)(n0 + (f >> 4)) * 512 + k0 + ((f & 15) << 2));
    }
  };

  loadX(0);
  for (int k0 = 0; k0 < 512; k0 += 64) {
    __syncthreads();
    #pragma unroll
    for (int i = 0; i < 4; ++i) {
      int f = (i << 8) + t;
      *(u16x8*)&Alds[f >> 3][(f & 7) << 3] = xa3[i];
    }
    #pragma unroll
    for (int i = 0; i < 8; ++i) {
      int f = (i << 8) + t;
      u32x2 p = { cvtpk(wb[i].x, wb[i].y), cvtpk(wb[i].z, wb[i].w) };
      *(u32x2*)&Blds[f >> 4][(f & 15) << 2] = p;
    }
    __syncthreads();
    if (k0 + 64 < 512) loadX(k0 + 64);

    #pragma unroll
    for (int kk = 0; kk < 2; ++kk) {
      bf16x8 af[4], bfr[4];
      #pragma unroll
      for (int mi = 0; mi < 4; ++mi)
        af[mi] = *(const bf16x8*)&Alds[(wr << 6) + (mi << 4) + lr][(kk << 5) + (lg << 3)];
      #pragma unroll
      for (int ni = 0; ni < 4; ++ni)
        bfr[ni] = *(const bf16x8*)&Blds[(wc << 6) + (ni << 4) + lr][(kk << 5) + (lg << 3)];
      #pragma unroll
      for (int mi = 0; mi < 4; ++mi)
        #pragma unroll
        for (int ni = 0; ni < 4; ++ni)
          acc[mi][ni] = __builtin_amdgcn_mfma_f32_16x16x32_bf16(af[mi], bfr[ni], acc[mi][ni], 0, 0, 0);
    }
  }

  #pragma unroll
  for (int mi = 0; mi < 4; ++mi) {
    #pragma unroll
    for (int ni = 0; ni < 4; ++ni) {
      const int e = n0 + (wc << 6) + (ni << 4) + lr;
      const int m = m0 + (wr << 6) + (mi << 4) + (lg << 2);
      const float bb = bias[e];
      size_t base = (size_t)m * 512 + e;
      #pragma unroll
      for (int r = 0; r < 4; ++r) Out[base + (size_t)r * 512] = acc[mi][ni][r] + bb;
    }
  }
}

// ---- Flash attention: r16 validated (C-init = -mrun, sequential mi, dual P,
//      dbuf 1-barrier staging). Grid 512 = 16 bh x 32 q-tiles. ----
__global__ __launch_bounds__(256, 2)
void attn_kernel(const u16* __restrict__ Qh, const u16* __restrict__ Kh,
                 const u16* __restrict__ Vt, u16* __restrict__ Xa)
{
  // u16 units: buf0 K [0..4095], buf0 V [4096..8191],
  //            buf1 K [8192..12287], buf1 V [12288..16383],
  //            P: 2 regions x 4 waves x [16][72]  [16384..25599]
  __shared__ alignas(1024) u16 smem[25600];

  const int t = threadIdx.x;
  const int lane = t & 63, w = t >> 6;
  const int lr = lane & 15, lg = lane >> 4;
  const int ob = ((blockIdx.x & 7) << 6) + (blockIdx.x >> 3);  // XCD-bijective (512%8==0)
  const int qb = ob & 31, bh = ob >> 5;
  const size_t qkbase = (size_t)bh * SEQ * DK;
  const size_t vbase  = (size_t)bh * DK * SEQ;
  u16* Pm[2] = { smem + 16384 + w * 1152, smem + 16384 + 4608 + w * 1152 };

  bf16x8 qf[2][2];
  #pragma unroll
  for (int mi = 0; mi < 2; ++mi)
    #pragma unroll
    for (int kk = 0; kk < 2; ++kk) {
      int qrow = (qb << 7) + (w << 5) + (mi << 4) + lr;
      qf[mi][kk] = *(const bf16x8*)(Qh + qkbase + (size_t)qrow * DK + (kk << 5) + (lg << 3));
    }

  bf16x8 onesf;
  {
    u16 one = (lr == 0) ? (u16)0x3F80 : (u16)0;
    #pragma unroll
    for (int j = 0; j < 8; ++j) onesf[j] = (short)one;
  }

  // mrun starts at 0: scores bounded (|s| << 127 in exp2 domain), so the
  // first tiles run un-shifted; defer-max keeps P <= 2^8 thereafter.
  float mrun[2] = {0.f, 0.f};
  f32x4 o[2][4], osum[2];
  #pragma unroll
  for (int mi = 0; mi < 2; ++mi) {
    #pragma unroll
    for (int dt = 0; dt < 4; ++dt) o[mi][dt] = (f32x4){0.f, 0.f, 0.f, 0.f};
    osum[mi] = (f32x4){0.f, 0.f, 0.f, 0.f};
  }

  const u16* Kg = Kh + qkbase;
  const u16* Vg = Vt + vbase;
  const int r0 = t >> 3, c0 = t & 7;
  const int r1 = r0 + 32;
  const int wk0 = r0 * 64 + ((c0 ^ (r0 & 7)) << 3);  // swizzled LDS offsets (u16)
  const int wk1 = r1 * 64 + ((c0 ^ (r1 & 7)) << 3);

  u16x8 kr0, kr1, vr0, vr1;
  auto GLOAD = [&](int it2) {
    const int kv0 = it2 << 6;
    kr0 = *(const u16x8*)(Kg + (size_t)(kv0 + r0) * 64 + (c0 << 3));
    kr1 = *(const u16x8*)(Kg + (size_t)(kv0 + r1) * 64 + (c0 << 3));
    vr0 = *(const u16x8*)(Vg + (size_t)r0 * SEQ + kv0 + (c0 << 3));
    vr1 = *(const u16x8*)(Vg + (size_t)r1 * SEQ + kv0 + (c0 << 3));
  };
  auto WRITE = [&](int buf) {
    u16* B = smem + buf * 8192;
    *(u16x8*)&B[wk0]        = kr0;
    *(u16x8*)&B[wk1]        = kr1;
    *(u16x8*)&B[4096 + wk0] = vr0;
    *(u16x8*)&B[4096 + wk1] = vr1;
  };

  GLOAD(0); WRITE(0); GLOAD(1);

  for (int it = 0; it < SEQ / 64; ++it) {
    const int cur = it & 1;
    __syncthreads();

    const u16* Kb = smem + cur * 8192;
    const u16* Vb = Kb + 4096;
    bf16x8 kf[4][2], vf[4][2];
    #pragma unroll
    for (int nt = 0; nt < 4; ++nt)
      #pragma unroll
      for (int kk = 0; kk < 2; ++kk) {
        const int off = ((nt << 4) + lr) * 64 + ((((kk << 2) + lg) ^ (lr & 7)) << 3);
        kf[nt][kk] = *(const bf16x8*)&Kb[off];
        vf[nt][kk] = *(const bf16x8*)&Vb[off];
      }

    if (it + 1 < SEQ / 64) WRITE(cur ^ 1);
    if (it + 2 < SEQ / 64) GLOAD(it + 2);

    #pragma unroll
    for (int mi = 0; mi < 2; ++mi) {
      u16* Pw = Pm[mi];
      const float mm = mrun[mi];
      // S' = K*Q^T - mm : shift baked into the accumulator init
      f32x4 s[4];
      const f32x4 ci = (f32x4){-mm, -mm, -mm, -mm};
      #pragma unroll
      for (int nt = 0; nt < 4; ++nt) s[nt] = ci;
      #pragma unroll
      for (int kk = 0; kk < 2; ++kk)
        #pragma unroll
        for (int nt = 0; nt < 4; ++nt)
          s[nt] = __builtin_amdgcn_mfma_f32_16x16x32_bf16(kf[nt][kk], qf[mi][kk], s[nt], 0, 0, 0);

      // lane-local partial max of shifted scores; ballot reduces across lanes
      float m0 = fmax3(s[0][0], s[0][1], s[0][2]);
      float m1 = fmax3(s[0][3], s[1][0], s[1][1]);
      float m2 = fmax3(s[1][2], s[1][3], s[2][0]);
      float m3 = fmax3(s[2][1], s[2][2], s[2][3]);
      float m4 = fmax3(s[3][0], s[3][1], s[3][2]);
      float pmax = fmaxf(fmax3(m0, m1, m2), fmax3(m3, m4, s[3][3]));

      if (!__all(pmax <= 8.f)) {  // rare fix-up: shift grew past THR=8
        float tmax = fmaxf(pmax, __shfl_xor(pmax, 16));
        tmax = fmaxf(tmax, __shfl_xor(tmax, 32));  // > 8 > 0 when taken
        float scl = fexp2(-tmax);
        mrun[mi] = mm + tmax;
        osum[mi][0] *= scl;
        #pragma unroll
        for (int dt = 0; dt < 4; ++dt) o[mi][dt] *= scl;
        #pragma unroll
        for (int nt = 0; nt < 4; ++nt) s[nt] = s[nt] - tmax;
      }

      // exps: no subtraction on the common path
      #pragma unroll
      for (int nt = 0; nt < 4; ++nt) {
        float e0 = fexp2(s[nt][0]), e1 = fexp2(s[nt][1]);
        float e2 = fexp2(s[nt][2]), e3 = fexp2(s[nt][3]);
        u32x2 pk2 = { cvtpk(e0, e1), cvtpk(e2, e3) };
        *(u32x2*)((char*)Pw + lr * 144 + (nt << 5) + (lg << 3)) = pk2;
      }

      // O^T += V * P^T ; l(row 0 of D) += ones * P^T
      #pragma unroll
      for (int kk = 0; kk < 2; ++kk) {
        bf16x8 pf = *(const bf16x8*)&Pw[lr * 72 + (kk << 5) + (lg << 3)];
        #pragma unroll
        for (int dt = 0; dt < 4; ++dt)
          o[mi][dt] = __builtin_amdgcn_mfma_f32_16x16x32_bf16(vf[dt][kk], pf, o[mi][dt], 0, 0, 0);
        osum[mi] = __builtin_amdgcn_mfma_f32_16x16x32_bf16(onesf, pf, osum[mi], 0, 0, 0);
      }
    }
  }
  __syncthreads();

  #pragma unroll
  for (int mi = 0; mi < 2; ++mi) {
    float lsum = __shfl(osum[mi][0], lr);
    float inv = 1.f / lsum;
    #pragma unroll
    for (int dt = 0; dt < 4; ++dt) {
      u16x4 v4 = { f2bf(o[mi][dt][0] * inv), f2bf(o[mi][dt][1] * inv),
                   f2bf(o[mi][dt][2] * inv), f2bf(o[mi][dt][3] * inv) };
      int row = (w << 5) + (mi << 4) + lr;
      *(u16x4*)&smem[row * 72 + (dt << 4) + (lg << 2)] = v4;
    }
  }
  __syncthreads();
  {
    const int b = bh >> 3, h = bh & 7;
    #pragma unroll
    for (int i = 0; i < 4; ++i) {
      int f = (i << 8) + t;
      int row = f >> 3, c8 = (f & 7) << 3;
      u16x8 val = *(const u16x8*)&smem[row * 72 + c8];
      *(u16x8*)(Xa + ((size_t)b * SEQ + (qb << 7) + row) * DM + (h << 6) + c8) = val;
    }
  }
}

extern "C" void kernel_launch(void* const* d_in, const int* in_sizes, int n_in,
                              void* d_out, int out_size, void* d_ws, size_t ws_size,
                              hipStream_t stream)
{
  const float* q  = (const float*)d_in[0];
  const float* k  = (const float*)d_in[1];
  const float* v  = (const float*)d_in[2];
  const float* wq = (const float*)d_in[3];
  const float* bq = (const float*)d_in[4];
  const float* wk = (const float*)d_in[5];
  const float* bk = (const float*)d_in[6];
  const float* wv = (const float*)d_in[7];
  const float* bv = (const float*)d_in[8];
  const float* wo = (const float*)d_in[9];
  const float* bo = (const float*)d_in[10];

  const size_t HS = (size_t)2 * NH * SEQ * DK;
  u16* Qh = (u16*)d_ws;
  u16* Kh = Qh + HS;
  u16* Vt = Kh + HS;
  u16* Xa = Vt + HS;

  gemm_qkv<<<768, 256, 0, stream>>>(q, k, v, wq, bq, wk, bk, wv, bv, Qh, Kh, Vt);
  attn_kernel<<<512, 256, 0, stream>>>(Qh, Kh, Vt, Xa);
  gemm_out<<<256, 256, 0, stream>>>(Xa, wo, bo, (float*)d_out);
}

// Round 19
// 129.324 us; speedup vs baseline: 1.3748x; 1.0001x over previous
//
#include <hip/hip_runtime.h>

#define DM 512
#define NH 8
#define DK 64
#define SEQ 4096

typedef short bf16x8 __attribute__((ext_vector_type(8)));
typedef float f32x4 __attribute__((ext_vector_type(4)));
typedef unsigned short u16;
typedef u16 u16x8 __attribute__((ext_vector_type(8)));
typedef u16 u16x4 __attribute__((ext_vector_type(4)));
typedef unsigned int u32;
typedef u32 u32x2 __attribute__((ext_vector_type(2)));

__device__ __forceinline__ u16 f2bf(float f) {
  union { float f; unsigned u; } v; v.f = f;
  unsigned r = v.u + 0x7fffu + ((v.u >> 16) & 1u);
  return (u16)(r >> 16);
}

__device__ __forceinline__ u32 cvtpk(float a, float b) {
  u32 r; asm("v_cvt_pk_bf16_f32 %0, %1, %2" : "=v"(r) : "v"(a), "v"(b)); return r;
}

__device__ __forceinline__ float fexp2(float x) {
  float r; asm("v_exp_f32 %0, %1" : "=v"(r) : "v"(x)); return r;
}

__device__ __forceinline__ float fmax3(float a, float b, float c) {
  return fmaxf(fmaxf(a, b), c);  // fuses to v_max3_f32
}

// ---- merged Q/K/V projection GEMM: 128x128 tiles, cvtpk staging.
// Grid 768 = 3 modes x 256, XCD-locality swizzle. __launch_bounds__(256,2):
// r17 showed (256,3) forces VGPR 84 -> spills xa/wb/acc -> 5x slowdown.
// mode 0: Qh * (0.125*log2 e); 1: Kh; 2: Vt (transposed).
__global__ __launch_bounds__(256, 2)
void gemm_qkv(const float* __restrict__ qx, const float* __restrict__ kx,
              const float* __restrict__ vx,
              const float* __restrict__ wq, const float* __restrict__ bq,
              const float* __restrict__ wk, const float* __restrict__ bk,
              const float* __restrict__ wv, const float* __restrict__ bv,
              u16* __restrict__ Qh, u16* __restrict__ Kh, u16* __restrict__ Vt)
{
  __shared__ alignas(16) u16 Alds[128][72];
  __shared__ alignas(16) u16 Blds[128][72];
  const int mode = blockIdx.x >> 8;
  const int d = blockIdx.x & 255;
  const int xcd = d & 7, inner = d >> 3;
  const int bx = (xcd << 3) + (inner >> 2);  // 0..63 m-tile
  const int by = inner & 3;                  // 0..3  n-tile
  const float* X = (mode == 0) ? qx : (mode == 1) ? kx : vx;
  const float* W = (mode == 0) ? wq : (mode == 1) ? wk : wv;
  const float* Bs = (mode == 0) ? bq : (mode == 1) ? bk : bv;

  const int t = threadIdx.x;
  const int m0 = bx << 7, n0 = by << 7;
  const int lane = t & 63, w = t >> 6;
  const int lr = lane & 15, lg = lane >> 4;
  const int wr = w >> 1, wc = w & 1;

  f32x4 acc[4][4];
  #pragma unroll
  for (int i = 0; i < 4; ++i)
    #pragma unroll
    for (int j = 0; j < 4; ++j) acc[i][j] = (f32x4){0.f, 0.f, 0.f, 0.f};

  float4 xa[8], wb[8];
  auto loadX = [&](int k0) {
    #pragma unroll
    for (int i = 0; i < 8; ++i) {
      int f = (i << 8) + t;
      xa[i] = *(const float4*)(X + (size_t)(m0 + (f >> 4)) * 512 + k0 + ((f & 15) << 2));
      wb[i] = *(const float4*)(W + (size_t)(n0 + (f >> 4)) * 512 + k0 + ((f & 15) << 2));
    }
  };

  loadX(0);
  for (int k0 = 0; k0 < 512; k0 += 64) {
    __syncthreads();
    #pragma unroll
    for (int i = 0; i < 8; ++i) {
      int f = (i << 8) + t;
      u32x2 pa = { cvtpk(xa[i].x, xa[i].y), cvtpk(xa[i].z, xa[i].w) };
      *(u32x2*)&Alds[f >> 4][(f & 15) << 2] = pa;
      u32x2 pb = { cvtpk(wb[i].x, wb[i].y), cvtpk(wb[i].z, wb[i].w) };
      *(u32x2*)&Blds[f >> 4][(f & 15) << 2] = pb;
    }
    __syncthreads();
    if (k0 + 64 < 512) loadX(k0 + 64);  // T14: prefetch hides under MFMA

    #pragma unroll
    for (int kk = 0; kk < 2; ++kk) {
      bf16x8 af[4], bfr[4];
      #pragma unroll
      for (int mi = 0; mi < 4; ++mi)
        af[mi] = *(const bf16x8*)&Alds[(wr << 6) + (mi << 4) + lr][(kk << 5) + (lg << 3)];
      #pragma unroll
      for (int ni = 0; ni < 4; ++ni)
        bfr[ni] = *(const bf16x8*)&Blds[(wc << 6) + (ni << 4) + lr][(kk << 5) + (lg << 3)];
      #pragma unroll
      for (int mi = 0; mi < 4; ++mi)
        #pragma unroll
        for (int ni = 0; ni < 4; ++ni)
          acc[mi][ni] = __builtin_amdgcn_mfma_f32_16x16x32_bf16(af[mi], bfr[ni], acc[mi][ni], 0, 0, 0);
    }
  }

  const float sc = (mode == 0) ? 0.18033688f : 1.0f;  // 0.125*log2(e) for Q
  #pragma unroll
  for (int mi = 0; mi < 4; ++mi) {
    #pragma unroll
    for (int ni = 0; ni < 4; ++ni) {
      const int e = n0 + (wc << 6) + (ni << 4) + lr;
      const int m = m0 + (wr << 6) + (mi << 4) + (lg << 2);
      const float bb = Bs[e];
      const int b = m >> 12, s = m & 4095, h = e >> 6, dk = e & 63;
      if (mode != 2) {
        u16* O = (mode == 0) ? Qh : Kh;
        size_t base = ((size_t)((b << 3) + h) * SEQ + s) * DK + dk;
        #pragma unroll
        for (int r = 0; r < 4; ++r)
          O[base + (size_t)r * DK] = f2bf((acc[mi][ni][r] + bb) * sc);
      } else {
        size_t base = ((size_t)((b << 3) + h) * DK + dk) * SEQ + s;
        u16x4 p = { f2bf(acc[mi][ni][0] + bb), f2bf(acc[mi][ni][1] + bb),
                    f2bf(acc[mi][ni][2] + bb), f2bf(acc[mi][ni][3] + bb) };
        *(u16x4*)(Vt + base) = p;
      }
    }
  }
}

// ---- output projection, 128x128 tiles, cvtpk W-staging, bf16 -> fp32 ----
__global__ __launch_bounds__(256, 2)
void gemm_out(const u16* __restrict__ Xa, const float* __restrict__ W,
              const float* __restrict__ bias, float* __restrict__ Out)
{
  __shared__ alignas(16) u16 Alds[128][72];
  __shared__ alignas(16) u16 Blds[128][72];
  const int d = blockIdx.x;
  const int xcd = d & 7, inner = d >> 3;
  const int bx = (xcd << 3) + (inner >> 2);
  const int by = inner & 3;

  const int t = threadIdx.x;
  const int m0 = bx << 7, n0 = by << 7;
  const int lane = t & 63, w = t >> 6;
  const int lr = lane & 15, lg = lane >> 4;
  const int wr = w >> 1, wc = w & 1;

  f32x4 acc[4][4];
  #pragma unroll
  for (int i = 0; i < 4; ++i)
    #pragma unroll
    for (int j = 0; j < 4; ++j) acc[i][j] = (f32x4){0.f, 0.f, 0.f, 0.f};

  u16x8 xa3[4]; float4 wb[8];
  auto loadX = [&](int k0) {
    #pragma unroll
    for (int i = 0; i < 4; ++i) {
      int f = (i << 8) + t;
      xa3[i] = *(const u16x8*)(Xa + (size_t)(m0 + (f >> 3)) * 512 + k0 + ((f & 7) << 3));
    }
    #pragma unroll
    for (int i = 0; i < 8; ++i) {
      int f = (i << 8) + t;
      wb[i] = *(const float4*)(W + (size_t)(n0 + (f >> 4)) * 512 + k0 + ((f & 15) << 2));
    }
  };

  loadX(0);
  for (int k0 = 0; k0 < 512; k0 += 64) {
    __syncthreads();
    #pragma unroll
    for (int i = 0; i < 4; ++i) {
      int f = (i << 8) + t;
      *(u16x8*)&Alds[f >> 3][(f & 7) << 3] = xa3[i];
    }
    #pragma unroll
    for (int i = 0; i < 8; ++i) {
      int f = (i << 8) + t;
      u32x2 p = { cvtpk(wb[i].x, wb[i].y), cvtpk(wb[i].z, wb[i].w) };
      *(u32x2*)&Blds[f >> 4][(f & 15) << 2] = p;
    }
    __syncthreads();
    if (k0 + 64 < 512) loadX(k0 + 64);

    #pragma unroll
    for (int kk = 0; kk < 2; ++kk) {
      bf16x8 af[4], bfr[4];
      #pragma unroll
      for (int mi = 0; mi < 4; ++mi)
        af[mi] = *(const bf16x8*)&Alds[(wr << 6) + (mi << 4) + lr][(kk << 5) + (lg << 3)];
      #pragma unroll
      for (int ni = 0; ni < 4; ++ni)
        bfr[ni] = *(const bf16x8*)&Blds[(wc << 6) + (ni << 4) + lr][(kk << 5) + (lg << 3)];
      #pragma unroll
      for (int mi = 0; mi < 4; ++mi)
        #pragma unroll
        for (int ni = 0; ni < 4; ++ni)
          acc[mi][ni] = __builtin_amdgcn_mfma_f32_16x16x32_bf16(af[mi], bfr[ni], acc[mi][ni], 0, 0, 0);
    }
  }

  #pragma unroll
  for (int mi = 0; mi < 4; ++mi) {
    #pragma unroll
    for (int ni = 0; ni < 4; ++ni) {
      const int e = n0 + (wc << 6) + (ni << 4) + lr;
      const int m = m0 + (wr << 6) + (mi << 4) + (lg << 2);
      const float bb = bias[e];
      size_t base = (size_t)m * 512 + e;
      #pragma unroll
      for (int r = 0; r < 4; ++r) Out[base + (size_t)r * 512] = acc[mi][ni][r] + bb;
    }
  }
}

// ---- Flash attention: r16 validated (C-init = -mrun, sequential mi, dual P,
//      dbuf 1-barrier staging). Grid 512 = 16 bh x 32 q-tiles. ----
__global__ __launch_bounds__(256, 2)
void attn_kernel(const u16* __restrict__ Qh, const u16* __restrict__ Kh,
                 const u16* __restrict__ Vt, u16* __restrict__ Xa)
{
  // u16 units: buf0 K [0..4095], buf0 V [4096..8191],
  //            buf1 K [8192..12287], buf1 V [12288..16383],
  //            P: 2 regions x 4 waves x [16][72]  [16384..25599]
  __shared__ alignas(1024) u16 smem[25600];

  const int t = threadIdx.x;
  const int lane = t & 63, w = t >> 6;
  const int lr = lane & 15, lg = lane >> 4;
  const int ob = ((blockIdx.x & 7) << 6) + (blockIdx.x >> 3);  // XCD-bijective (512%8==0)
  const int qb = ob & 31, bh = ob >> 5;
  const size_t qkbase = (size_t)bh * SEQ * DK;
  const size_t vbase  = (size_t)bh * DK * SEQ;
  u16* Pm[2] = { smem + 16384 + w * 1152, smem + 16384 + 4608 + w * 1152 };

  bf16x8 qf[2][2];
  #pragma unroll
  for (int mi = 0; mi < 2; ++mi)
    #pragma unroll
    for (int kk = 0; kk < 2; ++kk) {
      int qrow = (qb << 7) + (w << 5) + (mi << 4) + lr;
      qf[mi][kk] = *(const bf16x8*)(Qh + qkbase + (size_t)qrow * DK + (kk << 5) + (lg << 3));
    }

  bf16x8 onesf;
  {
    u16 one = (lr == 0) ? (u16)0x3F80 : (u16)0;
    #pragma unroll
    for (int j = 0; j < 8; ++j) onesf[j] = (short)one;
  }

  // mrun starts at 0: scores bounded (|s| << 127 in exp2 domain), so the
  // first tiles run un-shifted; defer-max keeps P <= 2^8 thereafter.
  float mrun[2] = {0.f, 0.f};
  f32x4 o[2][4], osum[2];
  #pragma unroll
  for (int mi = 0; mi < 2; ++mi) {
    #pragma unroll
    for (int dt = 0; dt < 4; ++dt) o[mi][dt] = (f32x4){0.f, 0.f, 0.f, 0.f};
    osum[mi] = (f32x4){0.f, 0.f, 0.f, 0.f};
  }

  const u16* Kg = Kh + qkbase;
  const u16* Vg = Vt + vbase;
  const int r0 = t >> 3, c0 = t & 7;
  const int r1 = r0 + 32;
  const int wk0 = r0 * 64 + ((c0 ^ (r0 & 7)) << 3);  // swizzled LDS offsets (u16)
  const int wk1 = r1 * 64 + ((c0 ^ (r1 & 7)) << 3);

  u16x8 kr0, kr1, vr0, vr1;
  auto GLOAD = [&](int it2) {
    const int kv0 = it2 << 6;
    kr0 = *(const u16x8*)(Kg + (size_t)(kv0 + r0) * 64 + (c0 << 3));
    kr1 = *(const u16x8*)(Kg + (size_t)(kv0 + r1) * 64 + (c0 << 3));
    vr0 = *(const u16x8*)(Vg + (size_t)r0 * SEQ + kv0 + (c0 << 3));
    vr1 = *(const u16x8*)(Vg + (size_t)r1 * SEQ + kv0 + (c0 << 3));
  };
  auto WRITE = [&](int buf) {
    u16* B = smem + buf * 8192;
    *(u16x8*)&B[wk0]        = kr0;
    *(u16x8*)&B[wk1]        = kr1;
    *(u16x8*)&B[4096 + wk0] = vr0;
    *(u16x8*)&B[4096 + wk1] = vr1;
  };

  GLOAD(0); WRITE(0); GLOAD(1);

  for (int it = 0; it < SEQ / 64; ++it) {
    const int cur = it & 1;
    __syncthreads();

    const u16* Kb = smem + cur * 8192;
    const u16* Vb = Kb + 4096;
    bf16x8 kf[4][2], vf[4][2];
    #pragma unroll
    for (int nt = 0; nt < 4; ++nt)
      #pragma unroll
      for (int kk = 0; kk < 2; ++kk) {
        const int off = ((nt << 4) + lr) * 64 + ((((kk << 2) + lg) ^ (lr & 7)) << 3);
        kf[nt][kk] = *(const bf16x8*)&Kb[off];
        vf[nt][kk] = *(const bf16x8*)&Vb[off];
      }

    if (it + 1 < SEQ / 64) WRITE(cur ^ 1);
    if (it + 2 < SEQ / 64) GLOAD(it + 2);

    #pragma unroll
    for (int mi = 0; mi < 2; ++mi) {
      u16* Pw = Pm[mi];
      const float mm = mrun[mi];
      // S' = K*Q^T - mm : shift baked into the accumulator init
      f32x4 s[4];
      const f32x4 ci = (f32x4){-mm, -mm, -mm, -mm};
      #pragma unroll
      for (int nt = 0; nt < 4; ++nt) s[nt] = ci;
      #pragma unroll
      for (int kk = 0; kk < 2; ++kk)
        #pragma unroll
        for (int nt = 0; nt < 4; ++nt)
          s[nt] = __builtin_amdgcn_mfma_f32_16x16x32_bf16(kf[nt][kk], qf[mi][kk], s[nt], 0, 0, 0);

      // lane-local partial max of shifted scores; ballot reduces across lanes
      float m0 = fmax3(s[0][0], s[0][1], s[0][2]);
      float m1 = fmax3(s[0][3], s[1][0], s[1][1]);
      float m2 = fmax3(s[1][2], s[1][3], s[2][0]);
      float m3 = fmax3(s[2][1], s[2][2], s[2][3]);
      float m4 = fmax3(s[3][0], s[3][1], s[3][2]);
      float pmax = fmaxf(fmax3(m0, m1, m2), fmax3(m3, m4, s[3][3]));

      if (!__all(pmax <= 8.f)) {  // rare fix-up: shift grew past THR=8
        float tmax = fmaxf(pmax, __shfl_xor(pmax, 16));
        tmax = fmaxf(tmax, __shfl_xor(tmax, 32));  // > 8 > 0 when taken
        float scl = fexp2(-tmax);
        mrun[mi] = mm + tmax;
        osum[mi][0] *= scl;
        #pragma unroll
        for (int dt = 0; dt < 4; ++dt) o[mi][dt] *= scl;
        #pragma unroll
        for (int nt = 0; nt < 4; ++nt) s[nt] = s[nt] - tmax;
      }

      // exps: no subtraction on the common path
      #pragma unroll
      for (int nt = 0; nt < 4; ++nt) {
        float e0 = fexp2(s[nt][0]), e1 = fexp2(s[nt][1]);
        float e2 = fexp2(s[nt][2]), e3 = fexp2(s[nt][3]);
        u32x2 pk2 = { cvtpk(e0, e1), cvtpk(e2, e3) };
        *(u32x2*)((char*)Pw + lr * 144 + (nt << 5) + (lg << 3)) = pk2;
      }

      // O^T += V * P^T ; l(row 0 of D) += ones * P^T
      #pragma unroll
      for (int kk = 0; kk < 2; ++kk) {
        bf16x8 pf = *(const bf16x8*)&Pw[lr * 72 + (kk << 5) + (lg << 3)];
        #pragma unroll
        for (int dt = 0; dt < 4; ++dt)
          o[mi][dt] = __builtin_amdgcn_mfma_f32_16x16x32_bf16(vf[dt][kk], pf, o[mi][dt], 0, 0, 0);
        osum[mi] = __builtin_amdgcn_mfma_f32_16x16x32_bf16(onesf, pf, osum[mi], 0, 0, 0);
      }
    }
  }
  __syncthreads();

  #pragma unroll
  for (int mi = 0; mi < 2; ++mi) {
    float lsum = __shfl(osum[mi][0], lr);
    float inv = 1.f / lsum;
    #pragma unroll
    for (int dt = 0; dt < 4; ++dt) {
      u16x4 v4 = { f2bf(o[mi][dt][0] * inv), f2bf(o[mi][dt][1] * inv),
                   f2bf(o[mi][dt][2] * inv), f2bf(o[mi][dt][3] * inv) };
      int row = (w << 5) + (mi << 4) + lr;
      *(u16x4*)&smem[row * 72 + (dt << 4) + (lg << 2)] = v4;
    }
  }
  __syncthreads();
  {
    const int b = bh >> 3, h = bh & 7;
    #pragma unroll
    for (int i = 0; i < 4; ++i) {
      int f = (i << 8) + t;
      int row = f >> 3, c8 = (f & 7) << 3;
      u16x8 val = *(const u16x8*)&smem[row * 72 + c8];
      *(u16x8*)(Xa + ((size_t)b * SEQ + (qb << 7) + row) * DM + (h << 6) + c8) = val;
    }
  }
}

extern "C" void kernel_launch(void* const* d_in, const int* in_sizes, int n_in,
                              void* d_out, int out_size, void* d_ws, size_t ws_size,
                              hipStream_t stream)
{
  const float* q  = (const float*)d_in[0];
  const float* k  = (const float*)d_in[1];
  const float* v  = (const float*)d_in[2];
  const float* wq = (const float*)d_in[3];
  const float* bq = (const float*)d_in[4];
  const float* wk = (const float*)d_in[5];
  const float* bk = (const float*)d_in[6];
  const float* wv = (const float*)d_in[7];
  const float* bv = (const float*)d_in[8];
  const float* wo = (const float*)d_in[9];
  const float* bo = (const float*)d_in[10];

  const size_t HS = (size_t)2 * NH * SEQ * DK;
  u16* Qh = (u16*)d_ws;
  u16* Kh = Qh + HS;
  u16* Vt = Kh + HS;
  u16* Xa = Vt + HS;

  gemm_qkv<<<768, 256, 0, stream>>>(q, k, v, wq, bq, wk, bk, wv, bv, Qh, Kh, Vt);
  attn_kernel<<<512, 256, 0, stream>>>(Qh, Kh, Vt, Xa);
  gemm_out<<<256, 256, 0, stream>>>(Xa, wo, bo, (float*)d_out);
}